// Round 2
// baseline (428.643 us; speedup 1.0000x reference)
//
#include <hip/hip_runtime.h>
#include <hip/hip_bf16.h>
#include <math.h>

typedef unsigned short u16;
typedef __bf16 bf16x8 __attribute__((ext_vector_type(8)));
typedef float f32x4 __attribute__((ext_vector_type(4)));

#define B_   2
#define T_   2048
#define D_   1024
#define H_   16
#define HD_  64
#define DFF_ 4096
#define M_TOK (B_*T_)

__device__ __forceinline__ u16 f2bf(float f){
  unsigned u = __float_as_uint(f);
  u += 0x7fff + ((u>>16)&1);          // round-nearest-even
  return (u16)(u>>16);
}

__device__ __forceinline__ void gl2lds16(const void* g, void* l){
  __builtin_amdgcn_global_load_lds((const __attribute__((address_space(1))) void*)g,
                                   (__attribute__((address_space(3))) void*)l, 16, 0, 0);
}

// ---------------- transpose f32 (K,N) -> bf16 (N,K) ----------------
__global__ __launch_bounds__(256) void k_transpose_bf16(const float* __restrict__ in,
                                                        u16* __restrict__ out, int K, int N){
  __shared__ float t[32][33];
  int bx = blockIdx.x*32, by = blockIdx.y*32;
  int tx = threadIdx.x, ty = threadIdx.y;
  #pragma unroll
  for(int i=ty;i<32;i+=8) t[i][tx] = in[(size_t)(by+i)*N + bx + tx];
  __syncthreads();
  #pragma unroll
  for(int i=ty;i<32;i+=8) out[(size_t)(bx+i)*K + by + tx] = f2bf(t[tx][i]);
}

// ---------------- RMSNorm (eps on the norm, per reference) -> bf16 ----------------
__global__ __launch_bounds__(256) void k_rmsnorm_bf16(const float* __restrict__ x,
                                                      const float* __restrict__ scale,
                                                      u16* __restrict__ out){
  int row = blockIdx.x;
  int tid = threadIdx.x;
  int lane = tid&63, wave = tid>>6;
  const float4* xr = (const float4*)(x + (size_t)row*D_);
  float4 v = xr[tid];
  float ss = v.x*v.x + v.y*v.y + v.z*v.z + v.w*v.w;
  #pragma unroll
  for(int o=1;o<64;o<<=1) ss += __shfl_xor(ss, o);
  __shared__ float red[4];
  if(lane==0) red[wave]=ss;
  __syncthreads();
  float tot = red[0]+red[1]+red[2]+red[3];
  float inv = 1.0f/(sqrtf(tot*(1.0f/D_)) + 1e-5f);
  const float4* sr = (const float4*)scale;
  float4 s4 = sr[tid];
  u16* o4 = out + (size_t)row*D_ + tid*4;
  o4[0]=f2bf(v.x*s4.x*inv); o4[1]=f2bf(v.y*s4.y*inv);
  o4[2]=f2bf(v.z*s4.z*inv); o4[3]=f2bf(v.w*s4.w*inv);
}

// ---------------- bf16 GEMM: C = A(MxK) * Bt(NxK)^T + bias [+res] ----------------
// EPI: 0 = bias -> bf16 out; 1 = bias + res(f32) -> f32 out; 2 = gelu(bias) -> bf16 out
template<int EPI>
__global__ __launch_bounds__(256) void k_gemm(const u16* __restrict__ A, const u16* __restrict__ Bt,
                                              const float* __restrict__ bias, const float* __restrict__ res,
                                              void* __restrict__ Cout, int M, int N, int K){
  __shared__ u16 As[128*32];
  __shared__ u16 Bs[128*32];
  int tid = threadIdx.x;
  int lane = tid&63, wave = tid>>6;
  int wr = wave>>1, wc = wave&1;
  int row0 = blockIdx.x*128, col0 = blockIdx.y*128;
  f32x4 acc[4][4];
  #pragma unroll
  for(int m=0;m<4;m++)
    #pragma unroll
    for(int n=0;n<4;n++) acc[m][n] = (f32x4){0.f,0.f,0.f,0.f};
  const u16* Ag = A + (size_t)row0*K;
  const u16* Bg = Bt + (size_t)col0*K;
  for(int k0=0;k0<K;k0+=32){
    __syncthreads();
    #pragma unroll
    for(int c=tid;c<512;c+=256){
      gl2lds16(Ag + (size_t)(c>>2)*K + k0 + (c&3)*8, (char*)As + c*16);
      gl2lds16(Bg + (size_t)(c>>2)*K + k0 + (c&3)*8, (char*)Bs + c*16);
    }
    __syncthreads();
    const u16* ab = As + (wr*64 + (lane&15))*32 + (lane>>4)*8;
    const u16* bb = Bs + (wc*64 + (lane&15))*32 + (lane>>4)*8;
    bf16x8 a[4], b[4];
    #pragma unroll
    for(int m=0;m<4;m++) a[m] = *(const bf16x8*)(ab + m*16*32);
    #pragma unroll
    for(int n=0;n<4;n++) b[n] = *(const bf16x8*)(bb + n*16*32);
    #pragma unroll
    for(int m=0;m<4;m++)
      #pragma unroll
      for(int n=0;n<4;n++)
        acc[m][n] = __builtin_amdgcn_mfma_f32_16x16x32_bf16(a[m], b[n], acc[m][n], 0,0,0);
  }
  #pragma unroll
  for(int m=0;m<4;m++){
    #pragma unroll
    for(int n=0;n<4;n++){
      #pragma unroll
      for(int r=0;r<4;r++){
        int row = row0 + wr*64 + m*16 + (lane>>4)*4 + r;
        int col = col0 + wc*64 + n*16 + (lane&15);
        float v = acc[m][n][r] + bias[col];
        if constexpr(EPI==1){
          ((float*)Cout)[(size_t)row*N + col] = v + res[(size_t)row*N + col];
        } else if constexpr(EPI==2){
          v = 0.5f*v*(1.0f + erff(v*0.70710678118f));
          ((u16*)Cout)[(size_t)row*N + col] = f2bf(v);
        } else {
          ((u16*)Cout)[(size_t)row*N + col] = f2bf(v);
        }
      }
    }
  }
}

// ---------------- flash attention: qkv bf16 (M_TOK x 3072) -> O bf16 (M_TOK x 1024) ----------------
__global__ __launch_bounds__(256) void k_attn(const u16* __restrict__ qkv, u16* __restrict__ O){
  int qt = blockIdx.x, h = blockIdx.y, b = blockIdx.z;
  int tid = threadIdx.x, lane = tid&63, wave = tid>>6;
  __shared__ u16 Ks[64*64];      // [key][d]
  __shared__ u16 Vt[64*64];      // [d][key]
  __shared__ u16 Ps[4][16*64];   // per-wave [q][key]
  size_t base = (size_t)b*T_*3072;
  int q0 = qt*64 + wave*16;
  const u16* qp = qkv + base + (size_t)(q0 + (lane&15))*3072 + h*64 + (lane>>4)*8;
  bf16x8 aq0 = *(const bf16x8*)qp;
  bf16x8 aq1 = *(const bf16x8*)(qp + 32);
  f32x4 oac[4];
  #pragma unroll
  for(int n=0;n<4;n++) oac[n] = (f32x4){0.f,0.f,0.f,0.f};
  float mrow[4] = {-1e30f,-1e30f,-1e30f,-1e30f};
  float lrow[4] = {0.f,0.f,0.f,0.f};

  for(int kt=0;kt<T_;kt+=64){
    __syncthreads();
    #pragma unroll
    for(int c=tid;c<512;c+=256){
      gl2lds16(qkv + base + (size_t)(kt + (c>>3))*3072 + 1024 + h*64 + (c&7)*8,
               (char*)Ks + c*16);
    }
    #pragma unroll
    for(int c=tid;c<512;c+=256){
      int key = c>>3, d0 = (c&7)*8;
      uint4 vv = *(const uint4*)(qkv + base + (size_t)(kt + key)*3072 + 2048 + h*64 + d0);
      const u16* ve = (const u16*)&vv;
      #pragma unroll
      for(int j=0;j<8;j++) Vt[(d0+j)*64 + key] = ve[j];
    }
    __syncthreads();

    f32x4 s[4];
    #pragma unroll
    for(int n=0;n<4;n++){
      const u16* kb = Ks + (n*16 + (lane&15))*64 + (lane>>4)*8;
      bf16x8 b0 = *(const bf16x8*)kb;
      bf16x8 b1 = *(const bf16x8*)(kb + 32);
      f32x4 z = (f32x4){0.f,0.f,0.f,0.f};
      z = __builtin_amdgcn_mfma_f32_16x16x32_bf16(aq0, b0, z, 0,0,0);
      z = __builtin_amdgcn_mfma_f32_16x16x32_bf16(aq1, b1, z, 0,0,0);
      s[n] = z;
    }
    #pragma unroll
    for(int r=0;r<4;r++){
      float s0=s[0][r]*0.125f, s1=s[1][r]*0.125f, s2=s[2][r]*0.125f, s3=s[3][r]*0.125f;
      float mx = fmaxf(fmaxf(s0,s1),fmaxf(s2,s3));
      #pragma unroll
      for(int msk=1; msk<16; msk<<=1) mx = fmaxf(mx, __shfl_xor(mx, msk));
      float nm = fmaxf(mrow[r], mx);
      float alpha = __expf(mrow[r] - nm);
      mrow[r] = nm;
      float p0 = __expf(s0-nm), p1=__expf(s1-nm), p2=__expf(s2-nm), p3=__expf(s3-nm);
      float psum = p0+p1+p2+p3;
      #pragma unroll
      for(int msk=1; msk<16; msk<<=1) psum += __shfl_xor(psum, msk);
      lrow[r] = lrow[r]*alpha + psum;
      int qrow = (lane>>4)*4 + r;
      u16* pr = Ps[wave] + qrow*64 + (lane&15);
      pr[0]  = f2bf(p0);
      pr[16] = f2bf(p1);
      pr[32] = f2bf(p2);
      pr[48] = f2bf(p3);
      #pragma unroll
      for(int n=0;n<4;n++) oac[n][r] *= alpha;
    }
    #pragma unroll
    for(int kk=0;kk<2;kk++){
      bf16x8 ap = *(const bf16x8*)(Ps[wave] + (lane&15)*64 + kk*32 + (lane>>4)*8);
      #pragma unroll
      for(int n=0;n<4;n++){
        bf16x8 bv = *(const bf16x8*)(Vt + ((lane&15) + n*16)*64 + kk*32 + (lane>>4)*8);
        oac[n] = __builtin_amdgcn_mfma_f32_16x16x32_bf16(ap, bv, oac[n], 0,0,0);
      }
    }
  }

  size_t obase = ((size_t)b*T_ + q0)*D_ + h*64;
  #pragma unroll
  for(int n=0;n<4;n++){
    #pragma unroll
    for(int r=0;r<4;r++){
      float v = oac[n][r] / lrow[r];
      O[obase + (size_t)((lane>>4)*4 + r)*D_ + n*16 + (lane&15)] = f2bf(v);
    }
  }
}

extern "C" void kernel_launch(void* const* d_in, const int* in_sizes, int n_in,
                              void* d_out, int out_size, void* d_ws, size_t ws_size,
                              hipStream_t stream){
  (void)in_sizes; (void)n_in; (void)out_size; (void)ws_size;
  const float* x      = (const float*)d_in[0];
  const float* scale1 = (const float*)d_in[1];
  const float* scale2 = (const float*)d_in[2];
  const float* Wqkv   = (const float*)d_in[3];
  const float* bqkv   = (const float*)d_in[4];
  const float* Wo     = (const float*)d_in[5];
  const float* bo     = (const float*)d_in[6];
  const float* W1     = (const float*)d_in[7];
  const float* b1     = (const float*)d_in[8];
  const float* W2     = (const float*)d_in[9];
  const float* b2     = (const float*)d_in[10];
  float* out = (float*)d_out;

  char* w = (char*)d_ws;
  u16* xn1   = (u16*)w;  w += (size_t)M_TOK*D_*2;
  u16* qkvb  = (u16*)w;  w += (size_t)M_TOK*3*D_*2;
  u16* Obuf  = (u16*)w;  w += (size_t)M_TOK*D_*2;
  float* x2  = (float*)w; w += (size_t)M_TOK*D_*4;
  u16* xn2   = (u16*)w;  w += (size_t)M_TOK*D_*2;
  u16* h1    = (u16*)w;  w += (size_t)M_TOK*DFF_*2;
  u16* Wqkvt = (u16*)w;  w += (size_t)3*D_*D_*2;
  u16* Wot   = (u16*)w;  w += (size_t)D_*D_*2;
  u16* W1t   = (u16*)w;  w += (size_t)D_*DFF_*2;
  u16* W2t   = (u16*)w;  w += (size_t)DFF_*D_*2;

  dim3 tb(32,8);
  k_transpose_bf16<<<dim3(3*D_/32, D_/32), tb, 0, stream>>>(Wqkv, Wqkvt, D_, 3*D_);
  k_transpose_bf16<<<dim3(D_/32,   D_/32), tb, 0, stream>>>(Wo,   Wot,   D_, D_);
  k_transpose_bf16<<<dim3(DFF_/32, D_/32), tb, 0, stream>>>(W1,   W1t,   D_, DFF_);
  k_transpose_bf16<<<dim3(D_/32, DFF_/32), tb, 0, stream>>>(W2,   W2t,   DFF_, D_);

  k_rmsnorm_bf16<<<M_TOK, 256, 0, stream>>>(x, scale1, xn1);
  k_gemm<0><<<dim3(M_TOK/128, 3*D_/128), 256, 0, stream>>>(xn1, Wqkvt, bqkv, nullptr, qkvb, M_TOK, 3*D_, D_);
  k_attn<<<dim3(T_/64, H_, B_), 256, 0, stream>>>(qkvb, Obuf);
  k_gemm<1><<<dim3(M_TOK/128, D_/128), 256, 0, stream>>>(Obuf, Wot, bo, x, x2, M_TOK, D_, D_);
  k_rmsnorm_bf16<<<M_TOK, 256, 0, stream>>>(x2, scale2, xn2);
  k_gemm<2><<<dim3(M_TOK/128, DFF_/128), 256, 0, stream>>>(xn2, W1t, b1, nullptr, h1, M_TOK, DFF_, D_);
  k_gemm<1><<<dim3(M_TOK/128, D_/128), 256, 0, stream>>>(h1, W2t, b2, x2, out, M_TOK, D_, DFF_);
}

// Round 3
// 301.178 us; speedup vs baseline: 1.4232x; 1.4232x over previous
//
#include <hip/hip_runtime.h>
#include <hip/hip_bf16.h>
#include <math.h>

typedef unsigned short u16;
typedef __bf16 bf16x8 __attribute__((ext_vector_type(8)));
typedef float f32x4 __attribute__((ext_vector_type(4)));
typedef unsigned int u32x2 __attribute__((ext_vector_type(2)));

#define B_   2
#define T_   2048
#define D_   1024
#define H_   16
#define HD_  64
#define DFF_ 4096
#define M_TOK (B_*T_)

__device__ __forceinline__ u16 f2bf(float f){
  unsigned u = __float_as_uint(f);
  u += 0x7fff + ((u>>16)&1);          // round-nearest-even
  return (u16)(u>>16);
}

__device__ __forceinline__ void gl2lds16(const void* g, void* l){
  __builtin_amdgcn_global_load_lds((const __attribute__((address_space(1))) void*)g,
                                   (__attribute__((address_space(3))) void*)l, 16, 0, 0);
}

__device__ __forceinline__ unsigned lds_u32(const void* p){
  return (unsigned)(uintptr_t)(const __attribute__((address_space(3))) void*)p;
}

__device__ __forceinline__ u32x2 tr_read(unsigned addr){
  u32x2 d;
  asm volatile("ds_read_b64_tr_b16 %0, %1" : "=v"(d) : "v"(addr));
  return d;
}
__device__ __forceinline__ u32x2 tr_read512(unsigned addr){
  u32x2 d;
  asm volatile("ds_read_b64_tr_b16 %0, %1 offset:512" : "=v"(d) : "v"(addr));
  return d;
}
__device__ __forceinline__ bf16x8 pack8(u32x2 a, u32x2 b){
  union { u32x2 u[2]; bf16x8 v; } x; x.u[0]=a; x.u[1]=b; return x.v;
}

// ---------------- transpose f32 (K,N) -> bf16 (N,K) ----------------
__global__ __launch_bounds__(256) void k_transpose_bf16(const float* __restrict__ in,
                                                        u16* __restrict__ out, int K, int N){
  __shared__ float t[32][33];
  int bx = blockIdx.x*32, by = blockIdx.y*32;
  int tx = threadIdx.x, ty = threadIdx.y;
  #pragma unroll
  for(int i=ty;i<32;i+=8) t[i][tx] = in[(size_t)(by+i)*N + bx + tx];
  __syncthreads();
  #pragma unroll
  for(int i=ty;i<32;i+=8) out[(size_t)(bx+i)*K + by + tx] = f2bf(t[tx][i]);
}

// ---------------- RMSNorm (eps on the norm, per reference) -> bf16 ----------------
__global__ __launch_bounds__(256) void k_rmsnorm_bf16(const float* __restrict__ x,
                                                      const float* __restrict__ scale,
                                                      u16* __restrict__ out){
  int row = blockIdx.x;
  int tid = threadIdx.x;
  int lane = tid&63, wave = tid>>6;
  const float4* xr = (const float4*)(x + (size_t)row*D_);
  float4 v = xr[tid];
  float ss = v.x*v.x + v.y*v.y + v.z*v.z + v.w*v.w;
  #pragma unroll
  for(int o=1;o<64;o<<=1) ss += __shfl_xor(ss, o);
  __shared__ float red[4];
  if(lane==0) red[wave]=ss;
  __syncthreads();
  float tot = red[0]+red[1]+red[2]+red[3];
  float inv = 1.0f/(sqrtf(tot*(1.0f/D_)) + 1e-5f);
  const float4* sr = (const float4*)scale;
  float4 s4 = sr[tid];
  u16* o4 = out + (size_t)row*D_ + tid*4;
  o4[0]=f2bf(v.x*s4.x*inv); o4[1]=f2bf(v.y*s4.y*inv);
  o4[2]=f2bf(v.z*s4.z*inv); o4[3]=f2bf(v.w*s4.w*inv);
}

// ---------------- bf16 GEMM: C = A(MxK) * Bt(NxK)^T + bias [+res] ----------------
// EPI: 0 = bias -> bf16 out; 1 = bias + res(f32) -> f32 out; 2 = gelu(bias) -> bf16 out
template<int EPI>
__global__ __launch_bounds__(256) void k_gemm(const u16* __restrict__ A, const u16* __restrict__ Bt,
                                              const float* __restrict__ bias, const float* __restrict__ res,
                                              void* __restrict__ Cout, int M, int N, int K){
  __shared__ u16 As[128*32];
  __shared__ u16 Bs[128*32];
  int tid = threadIdx.x;
  int lane = tid&63, wave = tid>>6;
  int wr = wave>>1, wc = wave&1;
  int row0 = blockIdx.x*128, col0 = blockIdx.y*128;
  f32x4 acc[4][4];
  #pragma unroll
  for(int m=0;m<4;m++)
    #pragma unroll
    for(int n=0;n<4;n++) acc[m][n] = (f32x4){0.f,0.f,0.f,0.f};
  const u16* Ag = A + (size_t)row0*K;
  const u16* Bg = Bt + (size_t)col0*K;
  for(int k0=0;k0<K;k0+=32){
    __syncthreads();
    #pragma unroll
    for(int c=tid;c<512;c+=256){
      gl2lds16(Ag + (size_t)(c>>2)*K + k0 + (c&3)*8, (char*)As + c*16);
      gl2lds16(Bg + (size_t)(c>>2)*K + k0 + (c&3)*8, (char*)Bs + c*16);
    }
    __syncthreads();
    const u16* ab = As + (wr*64 + (lane&15))*32 + (lane>>4)*8;
    const u16* bb = Bs + (wc*64 + (lane&15))*32 + (lane>>4)*8;
    bf16x8 a[4], b[4];
    #pragma unroll
    for(int m=0;m<4;m++) a[m] = *(const bf16x8*)(ab + m*16*32);
    #pragma unroll
    for(int n=0;n<4;n++) b[n] = *(const bf16x8*)(bb + n*16*32);
    #pragma unroll
    for(int m=0;m<4;m++)
      #pragma unroll
      for(int n=0;n<4;n++)
        acc[m][n] = __builtin_amdgcn_mfma_f32_16x16x32_bf16(a[m], b[n], acc[m][n], 0,0,0);
  }
  #pragma unroll
  for(int m=0;m<4;m++){
    #pragma unroll
    for(int n=0;n<4;n++){
      #pragma unroll
      for(int r=0;r<4;r++){
        int row = row0 + wr*64 + m*16 + (lane>>4)*4 + r;
        int col = col0 + wc*64 + n*16 + (lane&15);
        float v = acc[m][n][r] + bias[col];
        if constexpr(EPI==1){
          ((float*)Cout)[(size_t)row*N + col] = v + res[(size_t)row*N + col];
        } else if constexpr(EPI==2){
          v = 0.5f*v*(1.0f + erff(v*0.70710678118f));
          ((u16*)Cout)[(size_t)row*N + col] = f2bf(v);
        } else {
          ((u16*)Cout)[(size_t)row*N + col] = f2bf(v);
        }
      }
    }
  }
}

// ---------------- flash attention: qkv bf16 (M_TOK x 3072) -> O bf16 (M_TOK x 1024) ----------------
// K staged with XOR-swizzled source chunks (chunk ^= row&7) -> conflict-light ds_read_b128.
// V staged into subtiled [k/4][d/16][4][16] layout -> ds_read_b64_tr_b16 B-fragments.
// P per-wave LDS with XOR swizzle. Deferred-max online softmax, lane-local l partials.
__global__ __launch_bounds__(256,4) void k_attn(const u16* __restrict__ qkv, u16* __restrict__ O){
  __shared__ alignas(16) u16 Ks[2][4096];
  __shared__ alignas(16) u16 Vs[2][4096];
  __shared__ alignas(16) u16 Ps[4][1024];
  const int qt = blockIdx.x, h = blockIdx.y, b = blockIdx.z;
  const int tid = threadIdx.x, lane = tid&63, wave = tid>>6;
  const int lo = lane&15, hi = lane>>4, l7 = lane&7;
  const u16* qkvB = qkv + (size_t)b*T_*3072;
  const int hoff = h*64;

  // Q fragments (A-operand: row = lo, k = hi*8+j)
  const int q0 = qt*64 + wave*16;
  const u16* qp = qkvB + (size_t)(q0+lo)*3072 + hoff + hi*8;
  bf16x8 aq0 = *(const bf16x8*)qp;
  bf16x8 aq1 = *(const bf16x8*)(qp+32);

  // staging source offsets (u16 elements), per-thread chunks c and c+256
  size_t sK[2], sV[2];
  {
    int cc[2] = {tid, tid+256};
    #pragma unroll
    for(int i=0;i<2;i++){
      int c = cc[i];
      sK[i] = (size_t)(c>>3)*3072 + 1024 + hoff + (((c&7)^((c>>3)&7))<<3);
      int kv = ((c>>5)<<2) + ((c>>1)&3);
      int d0 = (((c&31)>>3)<<4) | ((c&1)<<3);
      sV[i] = (size_t)kv*3072 + 2048 + hoff + d0;
    }
  }
  // lane-dependent LDS byte offsets (swizzled); same formula serves K-frag and P-frag reads
  const unsigned kb0 = (unsigned)lo*128 + (unsigned)((hi^l7))*16;
  const unsigned kb1 = (unsigned)lo*128 + (unsigned)(((hi|4)^l7))*16;
  const unsigned vtr = (unsigned)hi*1024 + (unsigned)lo*2;

  f32x4 oac[4];
  #pragma unroll
  for(int n=0;n<4;n++) oac[n] = (f32x4){0.f,0.f,0.f,0.f};
  float mrow[4] = {-1e30f,-1e30f,-1e30f,-1e30f};
  float lrow[4] = {0.f,0.f,0.f,0.f};

  // prologue: stage tile 0 into buffer 0
  {
    char* kd = (char*)Ks[0]; char* vd = (char*)Vs[0];
    gl2lds16(qkvB + sK[0], kd + tid*16);
    gl2lds16(qkvB + sK[1], kd + tid*16 + 4096);
    gl2lds16(qkvB + sV[0], vd + tid*16);
    gl2lds16(qkvB + sV[1], vd + tid*16 + 4096);
  }
  int buf = 0;
  for(int t=0;t<T_/64;t++){
    __syncthreads();                      // drains vmcnt -> stage(t) complete
    if(t < T_/64-1){                      // prefetch tile t+1 into other buffer
      size_t koff = (size_t)(t+1)*64*3072;
      char* kd = (char*)Ks[buf^1]; char* vd = (char*)Vs[buf^1];
      gl2lds16(qkvB + koff + sK[0], kd + tid*16);
      gl2lds16(qkvB + koff + sK[1], kd + tid*16 + 4096);
      gl2lds16(qkvB + koff + sV[0], vd + tid*16);
      gl2lds16(qkvB + koff + sV[1], vd + tid*16 + 4096);
    }
    const char* K_ = (const char*)Ks[buf];
    u16* P_ = Ps[wave];

    // QK^T
    f32x4 s[4];
    #pragma unroll
    for(int n=0;n<4;n++){
      bf16x8 b0 = *(const bf16x8*)(K_ + n*2048 + kb0);
      bf16x8 b1 = *(const bf16x8*)(K_ + n*2048 + kb1);
      f32x4 z = (f32x4){0.f,0.f,0.f,0.f};
      z = __builtin_amdgcn_mfma_f32_16x16x32_bf16(aq0, b0, z, 0,0,0);
      z = __builtin_amdgcn_mfma_f32_16x16x32_bf16(aq1, b1, z, 0,0,0);
      s[n] = z;
    }

    // online softmax (deferred max; threshold 64 raw = 8 in exp-arg units)
    float mx[4]; int ok = 1;
    #pragma unroll
    for(int r=0;r<4;r++){
      mx[r] = fmaxf(fmaxf(s[0][r],s[1][r]),fmaxf(s[2][r],s[3][r]));
      ok &= (mx[r] <= mrow[r] + 64.0f) ? 1 : 0;
    }
    if(!__all(ok)){
      #pragma unroll
      for(int r=0;r<4;r++){
        float mm = mx[r];
        mm = fmaxf(mm, __shfl_xor(mm,1));
        mm = fmaxf(mm, __shfl_xor(mm,2));
        mm = fmaxf(mm, __shfl_xor(mm,4));
        mm = fmaxf(mm, __shfl_xor(mm,8));
        float nm = fmaxf(mrow[r], mm);
        float alpha = __expf((mrow[r]-nm)*0.125f);
        mrow[r] = nm;
        lrow[r] *= alpha;
        #pragma unroll
        for(int n=0;n<4;n++) oac[n][r] *= alpha;
      }
    }
    #pragma unroll
    for(int r=0;r<4;r++){
      float p[4];
      #pragma unroll
      for(int n=0;n<4;n++) p[n] = __expf((s[n][r]-mrow[r])*0.125f);
      lrow[r] += (p[0]+p[1])+(p[2]+p[3]);
      const int q = hi*4 + r;
      const unsigned X = (unsigned)(q&7)<<4;
      char* pb = (char*)P_ + q*128;
      #pragma unroll
      for(int n=0;n<4;n++)
        *(u16*)(pb + (((unsigned)(lo*2 + n*32))^X)) = f2bf(p[n]);
    }

    // PV: A = P (swizzled LDS), B = V via hardware transpose read
    const unsigned vsb = lds_u32(Vs[buf]);
    #pragma unroll
    for(int kk=0;kk<2;kk++){
      bf16x8 ap = *(const bf16x8*)((const char*)P_ + (kk==0 ? kb0 : kb1));
      u32x2 t0[4], t1[4];
      #pragma unroll
      for(int n=0;n<4;n++){
        unsigned a = vsb + vtr + (unsigned)kk*4096 + (unsigned)n*128;
        t0[n] = tr_read(a);
        t1[n] = tr_read512(a);
      }
      asm volatile("s_waitcnt lgkmcnt(0)" ::: "memory");
      __builtin_amdgcn_sched_barrier(0);
      #pragma unroll
      for(int n=0;n<4;n++){
        bf16x8 bv = pack8(t0[n], t1[n]);
        oac[n] = __builtin_amdgcn_mfma_f32_16x16x32_bf16(ap, bv, oac[n], 0,0,0);
      }
    }
    buf ^= 1;
  }

  // epilogue: reduce l across the 16-lane key groups, normalize, store
  #pragma unroll
  for(int r=0;r<4;r++){
    float lr = lrow[r];
    lr += __shfl_xor(lr,1);
    lr += __shfl_xor(lr,2);
    lr += __shfl_xor(lr,4);
    lr += __shfl_xor(lr,8);
    lrow[r] = 1.0f/lr;
  }
  size_t obase = ((size_t)b*T_ + q0)*D_ + hoff;
  #pragma unroll
  for(int n=0;n<4;n++)
    #pragma unroll
    for(int r=0;r<4;r++)
      O[obase + (size_t)(hi*4+r)*D_ + n*16 + lo] = f2bf(oac[n][r]*lrow[r]);
}

extern "C" void kernel_launch(void* const* d_in, const int* in_sizes, int n_in,
                              void* d_out, int out_size, void* d_ws, size_t ws_size,
                              hipStream_t stream){
  (void)in_sizes; (void)n_in; (void)out_size; (void)ws_size;
  const float* x      = (const float*)d_in[0];
  const float* scale1 = (const float*)d_in[1];
  const float* scale2 = (const float*)d_in[2];
  const float* Wqkv   = (const float*)d_in[3];
  const float* bqkv   = (const float*)d_in[4];
  const float* Wo     = (const float*)d_in[5];
  const float* bo     = (const float*)d_in[6];
  const float* W1     = (const float*)d_in[7];
  const float* b1     = (const float*)d_in[8];
  const float* W2     = (const float*)d_in[9];
  const float* b2     = (const float*)d_in[10];
  float* out = (float*)d_out;

  char* w = (char*)d_ws;
  u16* xn1   = (u16*)w;  w += (size_t)M_TOK*D_*2;
  u16* qkvb  = (u16*)w;  w += (size_t)M_TOK*3*D_*2;
  u16* Obuf  = (u16*)w;  w += (size_t)M_TOK*D_*2;
  float* x2  = (float*)w; w += (size_t)M_TOK*D_*4;
  u16* xn2   = (u16*)w;  w += (size_t)M_TOK*D_*2;
  u16* h1    = (u16*)w;  w += (size_t)M_TOK*DFF_*2;
  u16* Wqkvt = (u16*)w;  w += (size_t)3*D_*D_*2;
  u16* Wot   = (u16*)w;  w += (size_t)D_*D_*2;
  u16* W1t   = (u16*)w;  w += (size_t)D_*DFF_*2;
  u16* W2t   = (u16*)w;  w += (size_t)DFF_*D_*2;

  dim3 tb(32,8);
  k_transpose_bf16<<<dim3(3*D_/32, D_/32), tb, 0, stream>>>(Wqkv, Wqkvt, D_, 3*D_);
  k_transpose_bf16<<<dim3(D_/32,   D_/32), tb, 0, stream>>>(Wo,   Wot,   D_, D_);
  k_transpose_bf16<<<dim3(DFF_/32, D_/32), tb, 0, stream>>>(W1,   W1t,   D_, DFF_);
  k_transpose_bf16<<<dim3(D_/32, DFF_/32), tb, 0, stream>>>(W2,   W2t,   DFF_, D_);

  k_rmsnorm_bf16<<<M_TOK, 256, 0, stream>>>(x, scale1, xn1);
  k_gemm<0><<<dim3(M_TOK/128, 3*D_/128), 256, 0, stream>>>(xn1, Wqkvt, bqkv, nullptr, qkvb, M_TOK, 3*D_, D_);
  k_attn<<<dim3(T_/64, H_, B_), 256, 0, stream>>>(qkvb, Obuf);
  k_gemm<1><<<dim3(M_TOK/128, D_/128), 256, 0, stream>>>(Obuf, Wot, bo, x, x2, M_TOK, D_, D_);
  k_rmsnorm_bf16<<<M_TOK, 256, 0, stream>>>(x2, scale2, xn2);
  k_gemm<2><<<dim3(M_TOK/128, DFF_/128), 256, 0, stream>>>(xn2, W1t, b1, nullptr, h1, M_TOK, DFF_, D_);
  k_gemm<1><<<dim3(M_TOK/128, D_/128), 256, 0, stream>>>(h1, W2t, b2, x2, out, M_TOK, D_, DFF_);
}